// Round 19
// baseline (159.106 us; speedup 1.0000x reference)
//
#include <hip/hip_runtime.h>
#include <stdint.h>
#include <math.h>

typedef __attribute__((ext_vector_type(8))) short short8;
typedef __attribute__((ext_vector_type(4))) float f32x4;
typedef __attribute__((ext_vector_type(8))) float f32x8;
typedef __attribute__((ext_vector_type(16))) float f32x16;

#define DEV __device__ __forceinline__

DEV unsigned short f2bf(float f) {
  union { float f; unsigned int u; } v; v.f = f;
  return (unsigned short)((v.u + 0x7FFFu + ((v.u >> 16) & 1u)) >> 16);
}

DEV unsigned int pkbf(float a, float b) {  // low16 = bf16(a), high16 = bf16(b)
  unsigned int r;
  asm("v_cvt_pk_bf16_f32 %0, %1, %2" : "=v"(r) : "v"(a), "v"(b));
  return r;
}

#if __has_builtin(__builtin_amdgcn_permlane32_swap)
DEV float redsum32(float v) {
  typedef __attribute__((ext_vector_type(2))) unsigned int uint2v;
  union { float f; unsigned int u; } c; c.f = v;
  uint2v r = __builtin_amdgcn_permlane32_swap(c.u, c.u, false, false);
  union { unsigned int u; float f; } a, b; a.u = r[0]; b.u = r[1];
  return a.f + b.f;
}
#else
DEV float redsum32(float v) { return v + __shfl_xor(v, 32, 64); }
#endif

DEV void gld16(const void* g, void* lds) {
  __builtin_amdgcn_global_load_lds(
      (const __attribute__((address_space(1))) unsigned int*)g,
      (__attribute__((address_space(3))) unsigned int*)lds, 16, 0, 0);
}

// ---------------- fp32 -> bf16 convert (8 elems/thread) ----------------
__global__ __launch_bounds__(256) void cvt_bf16_kernel(
    const float* __restrict__ in, unsigned short* __restrict__ out, int n) {
  int i = (blockIdx.x * 256 + threadIdx.x) * 8;
  if (i >= n) return;
  const float4 a = *(const float4*)(in + i);
  const float4 b = *(const float4*)(in + i + 4);
  short8 o;
  o[0] = (short)f2bf(a.x); o[1] = (short)f2bf(a.y);
  o[2] = (short)f2bf(a.z); o[3] = (short)f2bf(a.w);
  o[4] = (short)f2bf(b.x); o[5] = (short)f2bf(b.y);
  o[6] = (short)f2bf(b.z); o[7] = (short)f2bf(b.w);
  *(short8*)(out + i) = o;
}

// ------------- transpose fp32 (K x N) -> bf16 (N x K) ------------------
__global__ __launch_bounds__(256) void transpose_w_kernel(
    const float* __restrict__ in, unsigned short* __restrict__ out,
    int Kdim, int Ndim) {
  __shared__ float t[32][33];
  const int nb = blockIdx.x * 32, kb = blockIdx.y * 32;
  const int tx = threadIdx.x & 31, ty = threadIdx.x >> 5;  // ty 0..7
#pragma unroll
  for (int i = 0; i < 32; i += 8)
    t[ty + i][tx] = in[(size_t)(kb + ty + i) * Ndim + nb + tx];
  __syncthreads();
#pragma unroll
  for (int i = 0; i < 32; i += 8)
    out[(size_t)(nb + ty + i) * Kdim + kb + tx] = f2bf(t[tx][ty + i]);
}

// ---------------- GEMM: C(MxN) = A(MxK,bf16) * Bt(NxK,bf16)^T ----------
// Within-XCD column-major tile walk (r17-proven); BK=64 two-half K-loop;
// through-LDS MODE0 epilogue writing Q,K,V in fragment order (r16-proven).
// r18 verbatim.
template<int M, int N, int K, int MODE>
__global__ __launch_bounds__(256)
void gemm_bt_kernel(const unsigned short* __restrict__ A,
                    const unsigned short* __restrict__ Bt,
                    unsigned short* __restrict__ Qd,
                    unsigned short* __restrict__ Kd,
                    unsigned short* __restrict__ Vd,
                    float* __restrict__ outC) {
  __shared__ __align__(16) unsigned short lsbuf[16384];  // 32 KB
  unsigned short* const lsA0 = lsbuf;
  unsigned short* const lsA1 = lsbuf + 4096;
  unsigned short* const lsB0 = lsbuf + 8192;
  unsigned short* const lsB1 = lsbuf + 12288;
  const int tid = threadIdx.x, wid = tid >> 6, lane = tid & 63;
  const int wr = wid >> 1, wc = wid & 1;
  constexpr int nx = N / 128;
  constexpr int nrow = M / 128;
  static_assert(nrow % 8 == 0, "XCD chunking needs (M/128) % 8 == 0");
  const int id0 = blockIdx.y * nx + blockIdx.x;      // dispatch index
  const int xcd = id0 & 7, j = id0 >> 3;             // round-robin XCD id
  const int row = xcd * (nrow / 8) + (j & (nrow / 8 - 1));
  const int colb = j / (nrow / 8);                   // column-major walk
  const int m0 = row * 128, n0 = colb * 128;

  f32x4 acc[4][4] = {};

  const int rA = lane >> 2, kA = (lane & 3) * 8;
  for (int kt = 0; kt < K / 64; ++kt) {
    __syncthreads();
#pragma unroll
    for (int c = 0; c < 2; ++c) {
      const int q = c * 4 + wid;
      const size_t ar = (size_t)(m0 + q * 16 + rA) * K + kt * 64 + kA;
      const size_t br = (size_t)(n0 + q * 16 + rA) * K + kt * 64 + kA;
      gld16(A  + ar,      lsA0 + q * 512);
      gld16(A  + ar + 32, lsA1 + q * 512);
      gld16(Bt + br,      lsB0 + q * 512);
      gld16(Bt + br + 32, lsB1 + q * 512);
    }
    __syncthreads();
#pragma unroll
    for (int kk = 0; kk < 2; ++kk) {
      const unsigned short* la = kk ? lsA1 : lsA0;
      const unsigned short* lb = kk ? lsB1 : lsB0;
      short8 af[4], bfr[4];
#pragma unroll
      for (int i = 0; i < 4; ++i) {
        af[i]  = *(const short8*)(la + (wr * 64 + i * 16 + (lane & 15)) * 32 + (lane >> 4) * 8);
        bfr[i] = *(const short8*)(lb + (wc * 64 + i * 16 + (lane & 15)) * 32 + (lane >> 4) * 8);
      }
#pragma unroll
      for (int i = 0; i < 4; ++i)
#pragma unroll
        for (int j2 = 0; j2 < 4; ++j2)
          acc[i][j2] = __builtin_amdgcn_mfma_f32_16x16x32_bf16(af[i], bfr[j2], acc[i][j2], 0, 0, 0);
    }
  }

  if constexpr (MODE == 0) {
    // ---- through-LDS epilogue: acc -> lsbuf (global-chunk order) ----
    __syncthreads();                         // all compute done, LDS free
    const int which = n0 >> 10;              // block-uniform (n0 128-aligned)
    const float scale = which == 0 ? 0.18033688f : 1.0f;  // rsqrt(hd)*log2e
#pragma unroll
    for (int i = 0; i < 4; ++i) {
      const int kt2 = wr * 2 + (i >> 1);     // local k-subtile (row>>5)
      const int sl = i & 1;                  // (row>>4)&1
#pragma unroll
      for (int j2 = 0; j2 < 4; ++j2) {
#pragma unroll
        for (int ii = 0; ii < 4; ++ii) {
          int off;
          if (which == 2) {
            // V frag: ((wc,kt2) chunk)*2048 + (f*64 + qlv + 32*(u>>3))*8 + (u&7)
            const int f = (j2 >> 1) * 2 + sl;
            const int qlv = (j2 & 1) * 16 + (lane & 15);
            const int g = (lane >> 4) * 4 + ii;
            const int u = (g & 3) | ((g & 4) << 1) | ((g & 8) >> 1);  // swap bits 2,3
            off = ((wc * 4 + kt2) * 4 + f) * 512 + (qlv + 32 * (u >> 3)) * 8 + (u & 7);
          } else {
            // Q/K frag: ((wc,kt2) chunk)*2048 + (sd*64 + ql' + 32*hi)*8 + jd
            const int qlp = (i & 1) * 16 + (lane >> 4) * 4 + ii;      // row&31
            const int hi = (lane >> 3) & 1;                            // (d>>3)&1
            off = ((wc * 4 + kt2) * 4 + j2) * 512 + (qlp + 32 * hi) * 8 + (lane & 7);
          }
          lsbuf[off] = f2bf(acc[i][j2][ii] * scale);
        }
      }
    }
    __syncthreads();
    // ---- coalesced copy-out: 8 chunks x 2048 shorts (16B/lane) ----
    unsigned short* dst = which == 0 ? Qd : (which == 1 ? Kd : Vd);
    const int b = m0 >> 11;                  // batch (blocks don't cross)
    const int ktg0 = (m0 & 2047) >> 5;       // global k-subtile base
    const int hh0 = (n0 >> 6) & 15;          // head base (+wc = +head2, no wrap)
#pragma unroll
    for (int c = 0; c < 8; ++c) {
      const int head2 = c >> 2, kt2c = c & 3;
      const size_t gbase =
          ((size_t)((b * 16 + hh0 + head2) * 64 + ktg0 + kt2c)) * 2048;
      *(short8*)(dst + gbase + tid * 8) = *(const short8*)(lsbuf + c * 2048 + tid * 8);
    }
  } else {
#pragma unroll
    for (int i = 0; i < 4; ++i)
#pragma unroll
      for (int j2 = 0; j2 < 4; ++j2) {
        const int rbase = m0 + wr * 64 + i * 16 + (lane >> 4) * 4;
        const int col = n0 + wc * 64 + j2 * 16 + (lane & 15);
#pragma unroll
        for (int ii = 0; ii < 4; ++ii)
          outC[(size_t)(rbase + ii) * N + col] = acc[i][j2][ii];
      }
  }
}

// ---------------- causal flash attention helpers (fragment-order loads) --
DEV void loadK4f(const unsigned short* Kfb, int kt, int lane, short8 kf[4]) {
  const unsigned short* p = Kfb + (size_t)kt * 2048 + lane * 8;
#pragma unroll
  for (int s = 0; s < 4; ++s) kf[s] = *(const short8*)(p + s * 512);
}
DEV void loadV4f(const unsigned short* Vfb, int kt, int lane, short8 vf[4]) {
  const unsigned short* p = Vfb + (size_t)kt * 2048 + lane * 8;
#pragma unroll
  for (int f = 0; f < 4; ++f) vf[f] = *(const short8*)(p + f * 512);
}

// One KV-tile step for NP parts (r18 verbatim): no-max softmax
// p = exp2(s) (scores bounded; masked -inf -> 0), vector l-accumulation.
template<int NP, bool MASK>
DEV void attn_step(int kv0, const short8 kf[4], const short8 qf[][4],
                   const int q0[], const short8 vf[4],
                   f32x8 lacc[], f32x16 o[][2], int ql, int h) {
  f32x16 st[NP];
  __builtin_amdgcn_s_setprio(1);
#pragma unroll
  for (int pp = 0; pp < NP; ++pp) {
    f32x16 s = {};
#pragma unroll
    for (int ss = 0; ss < 4; ++ss)
      s = __builtin_amdgcn_mfma_f32_32x32x16_bf16(kf[ss], qf[pp][ss], s, 0, 0, 0);
    st[pp] = s;
  }
  __builtin_amdgcn_s_setprio(0);
  if constexpr (MASK) {
#pragma unroll
    for (int r = 0; r < 16; ++r) {
      const int krow = (r & 3) + 8 * (r >> 2) + 4 * h;
      if (kv0 + krow > q0[0] + ql) st[0][r] = -INFINITY;
    }
  }
  union pk_t { unsigned int u[4]; short8 s8; };
  pk_t f0[NP], f1[NP];
#pragma unroll
  for (int pp = 0; pp < NP; ++pp) {
    f32x16 pv;
#pragma unroll
    for (int r = 0; r < 16; ++r) pv[r] = exp2f(st[pp][r]);
#pragma unroll
    for (int i = 0; i < 8; ++i) lacc[pp][i] += pv[2 * i] + pv[2 * i + 1];
#pragma unroll
    for (int i = 0; i < 4; ++i) {
      f0[pp].u[i] = pkbf(pv[2 * i], pv[2 * i + 1]);
      f1[pp].u[i] = pkbf(pv[8 + 2 * i], pv[9 + 2 * i]);
    }
  }
  __builtin_amdgcn_s_setprio(1);
#pragma unroll
  for (int pp = 0; pp < NP; ++pp) {
    o[pp][0] = __builtin_amdgcn_mfma_f32_32x32x16_bf16(vf[0], f0[pp].s8, o[pp][0], 0, 0, 0);
    o[pp][0] = __builtin_amdgcn_mfma_f32_32x32x16_bf16(vf[1], f1[pp].s8, o[pp][0], 0, 0, 0);
    o[pp][1] = __builtin_amdgcn_mfma_f32_32x32x16_bf16(vf[2], f0[pp].s8, o[pp][1], 0, 0, 0);
    o[pp][1] = __builtin_amdgcn_mfma_f32_32x32x16_bf16(vf[3], f1[pp].s8, o[pp][1], 0, 0, 0);
  }
  __builtin_amdgcn_s_setprio(0);
}

// ---------------- causal flash attention (r12 loop structure) ------------
// ROUND-19 CHANGE (only one): V prefetched one tile ahead, index-based,
// mirroring K's proven prefetch exactly. Rolling vf invariant: vf holds
// tile t's V at the top of every step. Prefetch indices: seg1/seg3 t+1
// (<= qtB <= 63), seg2 qtA+1 (<= 32), seg4 none. All in-bounds, no clamps.
__global__ __launch_bounds__(256, 2)
void attn_kernel(const unsigned short* __restrict__ Qf,
                 const unsigned short* __restrict__ Kf,
                 const unsigned short* __restrict__ Vf,
                 unsigned short* __restrict__ O) {
  const int bh = blockIdx.x & 63;
  const int w  = blockIdx.x >> 6;            // 0..7, walker 0 = heaviest
  const int wid = threadIdx.x >> 6, lane = threadIdx.x & 63;
  const int ql = lane & 31, h = lane >> 5;
  const int qtA = w * 4 + wid;               // 0..31
  const int qtB = 63 - qtA;                  // 32..63
  const int q0[2] = {qtA * 32, qtB * 32};

  const unsigned short* Qfb = Qf + (size_t)bh * 131072;
  const unsigned short* Kfb = Kf + (size_t)bh * 131072;
  const unsigned short* Vfb = Vf + (size_t)bh * 131072;

  short8 qf[2][4];
#pragma unroll
  for (int pp = 0; pp < 2; ++pp) {
    const int qt = pp == 0 ? qtA : qtB;
#pragma unroll
    for (int s = 0; s < 4; ++s)
      qf[pp][s] = *(const short8*)(Qfb + (size_t)qt * 2048 + s * 512 + lane * 8);
  }

  f32x16 o[2][2] = {};               // [part][d-half], O^T: col q, rows d
  f32x8 lacc[2] = {};                // vector l accumulators (summed at end)

  short8 kf[4], kn[4], vf[4], vn[4];
  loadK4f(Kfb, 0, lane, kf);
  loadV4f(Vfb, 0, lane, vf);

  // segment 1: t in [0, qtA) -- both parts, no mask
  for (int t = 0; t < qtA; ++t) {
    loadK4f(Kfb, t + 1, lane, kn);             // t+1 <= qtA <= 31: in-bounds
    loadV4f(Vfb, t + 1, lane, vn);
    attn_step<2, false>(0, kf, qf, q0, vf, lacc, o, ql, h);
#pragma unroll
    for (int s = 0; s < 4; ++s) { kf[s] = kn[s]; vf[s] = vn[s]; }
  }
  // segment 2: t = qtA -- both parts, mask part A (B unmasked: qtA < qtB)
  {
    loadK4f(Kfb, qtA + 1, lane, kn);           // qtA+1 <= 32: in-bounds
    loadV4f(Vfb, qtA + 1, lane, vn);
    attn_step<2, true>(qtA * 32, kf, qf, q0, vf, lacc, o, ql, h);
#pragma unroll
    for (int s = 0; s < 4; ++s) { kf[s] = kn[s]; vf[s] = vn[s]; }
  }
  // segment 3: t in (qtA, qtB) -- part B only
  for (int t = qtA + 1; t < qtB; ++t) {
    loadK4f(Kfb, t + 1, lane, kn);             // t+1 <= qtB <= 63: in-bounds
    loadV4f(Vfb, t + 1, lane, vn);
    attn_step<1, false>(0, kf, &qf[1], &q0[1], vf, &lacc[1], &o[1], ql, h);
#pragma unroll
    for (int s = 0; s < 4; ++s) { kf[s] = kn[s]; vf[s] = vn[s]; }
  }
  // segment 4: t = qtB -- part B, masked, no prefetch (vf/kf already hold qtB)
  attn_step<1, true>(qtB * 32, kf, &qf[1], &q0[1], vf, &lacc[1], &o[1], ql, h);

  // epilogue: horizontal l-sum (once), cross-half merge (once), store
  const int b = bh >> 4, head = bh & 15;
#pragma unroll
  for (int pp = 0; pp < 2; ++pp) {
    float ls = ((lacc[pp][0] + lacc[pp][1]) + (lacc[pp][2] + lacc[pp][3])) +
               ((lacc[pp][4] + lacc[pp][5]) + (lacc[pp][6] + lacc[pp][7]));
    const float inv = 1.0f / redsum32(ls);
    unsigned short* Orow = O + ((size_t)(b * 2048 + q0[pp] + ql)) * 1024 + head * 64;
#pragma unroll
    for (int g = 0; g < 4; ++g) {
      {
        const unsigned int lo = pkbf(o[pp][0][g * 4 + 0] * inv, o[pp][0][g * 4 + 1] * inv);
        const unsigned int hi = pkbf(o[pp][0][g * 4 + 2] * inv, o[pp][0][g * 4 + 3] * inv);
        uint2 val; val.x = lo; val.y = hi;
        *(uint2*)(Orow + 8 * g + 4 * h) = val;
      }
      {
        const unsigned int lo = pkbf(o[pp][1][g * 4 + 0] * inv, o[pp][1][g * 4 + 1] * inv);
        const unsigned int hi = pkbf(o[pp][1][g * 4 + 2] * inv, o[pp][1][g * 4 + 3] * inv);
        uint2 val; val.x = lo; val.y = hi;
        *(uint2*)(Orow + 32 + 8 * g + 4 * h) = val;
      }
    }
  }
}

extern "C" void kernel_launch(void* const* d_in, const int* in_sizes, int n_in,
                              void* d_out, int out_size, void* d_ws, size_t ws_size,
                              hipStream_t stream) {
  (void)in_sizes; (void)n_in; (void)out_size; (void)ws_size;
  const float* x      = (const float*)d_in[0];
  const float* w_qkv  = (const float*)d_in[1];
  const float* w_proj = (const float*)d_in[2];
  float* out = (float*)d_out;
  char* ws = (char*)d_ws;

  unsigned short* x_bf   = (unsigned short*)(ws);              // 16 MB (reused as attn_out)
  unsigned short* wqT    = (unsigned short*)(ws + 16777216);   // 6 MB
  unsigned short* wpT    = (unsigned short*)(ws + 23068672);   // 2 MB
  unsigned short* Qfd    = (unsigned short*)(ws + 25165824);   // 16 MB (fragment order)
  unsigned short* Kfd    = (unsigned short*)(ws + 41943040);   // 16 MB (fragment order)
  unsigned short* Vfd    = (unsigned short*)(ws + 58720256);   // 16 MB (fragment order, fused)
  unsigned short* attn_o = x_bf;

  cvt_bf16_kernel<<<4096, 256, 0, stream>>>(x, x_bf, 8388608);
  transpose_w_kernel<<<dim3(96, 32), 256, 0, stream>>>(w_qkv, wqT, 1024, 3072);
  transpose_w_kernel<<<dim3(32, 32), 256, 0, stream>>>(w_proj, wpT, 1024, 1024);
  gemm_bt_kernel<8192, 3072, 1024, 0><<<dim3(24, 64), 256, 0, stream>>>(
      x_bf, wqT, Qfd, Kfd, Vfd, nullptr);
  attn_kernel<<<512, 256, 0, stream>>>(Qfd, Kfd, Vfd, attn_o);
  gemm_bt_kernel<8192, 1024, 1024, 1><<<dim3(8, 64), 256, 0, stream>>>(
      attn_o, wpT, nullptr, nullptr, nullptr, out);
}

// Round 20
// 156.761 us; speedup vs baseline: 1.0150x; 1.0150x over previous
//
#include <hip/hip_runtime.h>
#include <stdint.h>
#include <math.h>

typedef __attribute__((ext_vector_type(8))) short short8;
typedef __attribute__((ext_vector_type(4))) float f32x4;
typedef __attribute__((ext_vector_type(8))) float f32x8;
typedef __attribute__((ext_vector_type(16))) float f32x16;

#define DEV __device__ __forceinline__

DEV unsigned short f2bf(float f) {
  union { float f; unsigned int u; } v; v.f = f;
  return (unsigned short)((v.u + 0x7FFFu + ((v.u >> 16) & 1u)) >> 16);
}

DEV unsigned int pkbf(float a, float b) {  // low16 = bf16(a), high16 = bf16(b)
  unsigned int r;
  asm("v_cvt_pk_bf16_f32 %0, %1, %2" : "=v"(r) : "v"(a), "v"(b));
  return r;
}

#if __has_builtin(__builtin_amdgcn_permlane32_swap)
DEV float redsum32(float v) {
  typedef __attribute__((ext_vector_type(2))) unsigned int uint2v;
  union { float f; unsigned int u; } c; c.f = v;
  uint2v r = __builtin_amdgcn_permlane32_swap(c.u, c.u, false, false);
  union { unsigned int u; float f; } a, b; a.u = r[0]; b.u = r[1];
  return a.f + b.f;
}
#else
DEV float redsum32(float v) { return v + __shfl_xor(v, 32, 64); }
#endif

DEV void gld16(const void* g, void* lds) {
  __builtin_amdgcn_global_load_lds(
      (const __attribute__((address_space(1))) unsigned int*)g,
      (__attribute__((address_space(3))) unsigned int*)lds, 16, 0, 0);
}

// ---------------- fp32 -> bf16 convert (8 elems/thread) ----------------
__global__ __launch_bounds__(256) void cvt_bf16_kernel(
    const float* __restrict__ in, unsigned short* __restrict__ out, int n) {
  int i = (blockIdx.x * 256 + threadIdx.x) * 8;
  if (i >= n) return;
  const float4 a = *(const float4*)(in + i);
  const float4 b = *(const float4*)(in + i + 4);
  short8 o;
  o[0] = (short)f2bf(a.x); o[1] = (short)f2bf(a.y);
  o[2] = (short)f2bf(a.z); o[3] = (short)f2bf(a.w);
  o[4] = (short)f2bf(b.x); o[5] = (short)f2bf(b.y);
  o[6] = (short)f2bf(b.z); o[7] = (short)f2bf(b.w);
  *(short8*)(out + i) = o;
}

// ------------- transpose fp32 (K x N) -> bf16 (N x K) ------------------
__global__ __launch_bounds__(256) void transpose_w_kernel(
    const float* __restrict__ in, unsigned short* __restrict__ out,
    int Kdim, int Ndim) {
  __shared__ float t[32][33];
  const int nb = blockIdx.x * 32, kb = blockIdx.y * 32;
  const int tx = threadIdx.x & 31, ty = threadIdx.x >> 5;  // ty 0..7
#pragma unroll
  for (int i = 0; i < 32; i += 8)
    t[ty + i][tx] = in[(size_t)(kb + ty + i) * Ndim + nb + tx];
  __syncthreads();
#pragma unroll
  for (int i = 0; i < 32; i += 8)
    out[(size_t)(nb + ty + i) * Kdim + kb + tx] = f2bf(t[tx][ty + i]);
}

// ---------------- GEMM: C(MxN) = A(MxK,bf16) * Bt(NxK,bf16)^T ----------
// Within-XCD column-major tile walk (r17-proven); BK=64 two-half K-loop;
// through-LDS MODE0 epilogue writing Q,K,V in fragment order (r16-proven).
template<int M, int N, int K, int MODE>
__global__ __launch_bounds__(256)
void gemm_bt_kernel(const unsigned short* __restrict__ A,
                    const unsigned short* __restrict__ Bt,
                    unsigned short* __restrict__ Qd,
                    unsigned short* __restrict__ Kd,
                    unsigned short* __restrict__ Vd,
                    float* __restrict__ outC) {
  __shared__ __align__(16) unsigned short lsbuf[16384];  // 32 KB
  unsigned short* const lsA0 = lsbuf;
  unsigned short* const lsA1 = lsbuf + 4096;
  unsigned short* const lsB0 = lsbuf + 8192;
  unsigned short* const lsB1 = lsbuf + 12288;
  const int tid = threadIdx.x, wid = tid >> 6, lane = tid & 63;
  const int wr = wid >> 1, wc = wid & 1;
  constexpr int nx = N / 128;
  constexpr int nrow = M / 128;
  static_assert(nrow % 8 == 0, "XCD chunking needs (M/128) % 8 == 0");
  const int id0 = blockIdx.y * nx + blockIdx.x;      // dispatch index
  const int xcd = id0 & 7, j = id0 >> 3;             // round-robin XCD id
  const int row = xcd * (nrow / 8) + (j & (nrow / 8 - 1));
  const int colb = j / (nrow / 8);                   // column-major walk
  const int m0 = row * 128, n0 = colb * 128;

  f32x4 acc[4][4] = {};

  const int rA = lane >> 2, kA = (lane & 3) * 8;
  for (int kt = 0; kt < K / 64; ++kt) {
    __syncthreads();
#pragma unroll
    for (int c = 0; c < 2; ++c) {
      const int q = c * 4 + wid;
      const size_t ar = (size_t)(m0 + q * 16 + rA) * K + kt * 64 + kA;
      const size_t br = (size_t)(n0 + q * 16 + rA) * K + kt * 64 + kA;
      gld16(A  + ar,      lsA0 + q * 512);
      gld16(A  + ar + 32, lsA1 + q * 512);
      gld16(Bt + br,      lsB0 + q * 512);
      gld16(Bt + br + 32, lsB1 + q * 512);
    }
    __syncthreads();
#pragma unroll
    for (int kk = 0; kk < 2; ++kk) {
      const unsigned short* la = kk ? lsA1 : lsA0;
      const unsigned short* lb = kk ? lsB1 : lsB0;
      short8 af[4], bfr[4];
#pragma unroll
      for (int i = 0; i < 4; ++i) {
        af[i]  = *(const short8*)(la + (wr * 64 + i * 16 + (lane & 15)) * 32 + (lane >> 4) * 8);
        bfr[i] = *(const short8*)(lb + (wc * 64 + i * 16 + (lane & 15)) * 32 + (lane >> 4) * 8);
      }
#pragma unroll
      for (int i = 0; i < 4; ++i)
#pragma unroll
        for (int j2 = 0; j2 < 4; ++j2)
          acc[i][j2] = __builtin_amdgcn_mfma_f32_16x16x32_bf16(af[i], bfr[j2], acc[i][j2], 0, 0, 0);
    }
  }

  if constexpr (MODE == 0) {
    // ---- through-LDS epilogue: acc -> lsbuf (global-chunk order) ----
    __syncthreads();                         // all compute done, LDS free
    const int which = n0 >> 10;              // block-uniform (n0 128-aligned)
    const float scale = which == 0 ? 0.18033688f : 1.0f;  // rsqrt(hd)*log2e
#pragma unroll
    for (int i = 0; i < 4; ++i) {
      const int kt2 = wr * 2 + (i >> 1);     // local k-subtile (row>>5)
      const int sl = i & 1;                  // (row>>4)&1
#pragma unroll
      for (int j2 = 0; j2 < 4; ++j2) {
#pragma unroll
        for (int ii = 0; ii < 4; ++ii) {
          int off;
          if (which == 2) {
            // V frag: ((wc,kt2) chunk)*2048 + (f*64 + qlv + 32*(u>>3))*8 + (u&7)
            const int f = (j2 >> 1) * 2 + sl;
            const int qlv = (j2 & 1) * 16 + (lane & 15);
            const int g = (lane >> 4) * 4 + ii;
            const int u = (g & 3) | ((g & 4) << 1) | ((g & 8) >> 1);  // swap bits 2,3
            off = ((wc * 4 + kt2) * 4 + f) * 512 + (qlv + 32 * (u >> 3)) * 8 + (u & 7);
          } else {
            // Q/K frag: ((wc,kt2) chunk)*2048 + (sd*64 + ql' + 32*hi)*8 + jd
            const int qlp = (i & 1) * 16 + (lane >> 4) * 4 + ii;      // row&31
            const int hi = (lane >> 3) & 1;                            // (d>>3)&1
            off = ((wc * 4 + kt2) * 4 + j2) * 512 + (qlp + 32 * hi) * 8 + (lane & 7);
          }
          lsbuf[off] = f2bf(acc[i][j2][ii] * scale);
        }
      }
    }
    __syncthreads();
    // ---- coalesced copy-out: 8 chunks x 2048 shorts (16B/lane) ----
    unsigned short* dst = which == 0 ? Qd : (which == 1 ? Kd : Vd);
    const int b = m0 >> 11;                  // batch (blocks don't cross)
    const int ktg0 = (m0 & 2047) >> 5;       // global k-subtile base
    const int hh0 = (n0 >> 6) & 15;          // head base (+wc = +head2, no wrap)
#pragma unroll
    for (int c = 0; c < 8; ++c) {
      const int head2 = c >> 2, kt2c = c & 3;
      const size_t gbase =
          ((size_t)((b * 16 + hh0 + head2) * 64 + ktg0 + kt2c)) * 2048;
      *(short8*)(dst + gbase + tid * 8) = *(const short8*)(lsbuf + c * 2048 + tid * 8);
    }
  } else {
#pragma unroll
    for (int i = 0; i < 4; ++i)
#pragma unroll
      for (int j2 = 0; j2 < 4; ++j2) {
        const int rbase = m0 + wr * 64 + i * 16 + (lane >> 4) * 4;
        const int col = n0 + wc * 64 + j2 * 16 + (lane & 15);
#pragma unroll
        for (int ii = 0; ii < 4; ++ii)
          outC[(size_t)(rbase + ii) * N + col] = acc[i][j2][ii];
      }
  }
}

// ---------------- causal flash attention helpers (fragment-order loads) --
DEV void loadK4f(const unsigned short* Kfb, int kt, int lane, short8 kf[4]) {
  const unsigned short* p = Kfb + (size_t)kt * 2048 + lane * 8;
#pragma unroll
  for (int s = 0; s < 4; ++s) kf[s] = *(const short8*)(p + s * 512);
}
DEV void loadV4f(const unsigned short* Vfb, int kt, int lane, short8 vf[4]) {
  const unsigned short* p = Vfb + (size_t)kt * 2048 + lane * 8;
#pragma unroll
  for (int f = 0; f < 4; ++f) vf[f] = *(const short8*)(p + f * 512);
}

// One KV-tile step for NP parts: no-max softmax p = exp2(s) (scores
// bounded; masked -inf -> 0), vector l-accumulation (r18-proven).
template<int NP, bool MASK>
DEV void attn_step(int kv0, const short8 kf[4], const short8 qf[][4],
                   const int q0[], const short8 vf[4],
                   f32x8 lacc[], f32x16 o[][2], int ql, int h) {
  f32x16 st[NP];
  __builtin_amdgcn_s_setprio(1);
#pragma unroll
  for (int pp = 0; pp < NP; ++pp) {
    f32x16 s = {};
#pragma unroll
    for (int ss = 0; ss < 4; ++ss)
      s = __builtin_amdgcn_mfma_f32_32x32x16_bf16(kf[ss], qf[pp][ss], s, 0, 0, 0);
    st[pp] = s;
  }
  __builtin_amdgcn_s_setprio(0);
  if constexpr (MASK) {
#pragma unroll
    for (int r = 0; r < 16; ++r) {
      const int krow = (r & 3) + 8 * (r >> 2) + 4 * h;
      if (kv0 + krow > q0[0] + ql) st[0][r] = -INFINITY;
    }
  }
  union pk_t { unsigned int u[4]; short8 s8; };
  pk_t f0[NP], f1[NP];
#pragma unroll
  for (int pp = 0; pp < NP; ++pp) {
    f32x16 pv;
#pragma unroll
    for (int r = 0; r < 16; ++r) pv[r] = exp2f(st[pp][r]);
#pragma unroll
    for (int i = 0; i < 8; ++i) lacc[pp][i] += pv[2 * i] + pv[2 * i + 1];
#pragma unroll
    for (int i = 0; i < 4; ++i) {
      f0[pp].u[i] = pkbf(pv[2 * i], pv[2 * i + 1]);
      f1[pp].u[i] = pkbf(pv[8 + 2 * i], pv[9 + 2 * i]);
    }
  }
  __builtin_amdgcn_s_setprio(1);
#pragma unroll
  for (int pp = 0; pp < NP; ++pp) {
    o[pp][0] = __builtin_amdgcn_mfma_f32_32x32x16_bf16(vf[0], f0[pp].s8, o[pp][0], 0, 0, 0);
    o[pp][0] = __builtin_amdgcn_mfma_f32_32x32x16_bf16(vf[1], f1[pp].s8, o[pp][0], 0, 0, 0);
    o[pp][1] = __builtin_amdgcn_mfma_f32_32x32x16_bf16(vf[2], f0[pp].s8, o[pp][1], 0, 0, 0);
    o[pp][1] = __builtin_amdgcn_mfma_f32_32x32x16_bf16(vf[3], f1[pp].s8, o[pp][1], 0, 0, 0);
  }
  __builtin_amdgcn_s_setprio(0);
}

// ---------------- causal flash attention (r18 verbatim: best measured) ---
__global__ __launch_bounds__(256, 2)
void attn_kernel(const unsigned short* __restrict__ Qf,
                 const unsigned short* __restrict__ Kf,
                 const unsigned short* __restrict__ Vf,
                 unsigned short* __restrict__ O) {
  const int bh = blockIdx.x & 63;
  const int w  = blockIdx.x >> 6;            // 0..7, walker 0 = heaviest
  const int wid = threadIdx.x >> 6, lane = threadIdx.x & 63;
  const int ql = lane & 31, h = lane >> 5;
  const int qtA = w * 4 + wid;               // 0..31
  const int qtB = 63 - qtA;                  // 32..63
  const int q0[2] = {qtA * 32, qtB * 32};

  const unsigned short* Qfb = Qf + (size_t)bh * 131072;
  const unsigned short* Kfb = Kf + (size_t)bh * 131072;
  const unsigned short* Vfb = Vf + (size_t)bh * 131072;

  short8 qf[2][4];
#pragma unroll
  for (int pp = 0; pp < 2; ++pp) {
    const int qt = pp == 0 ? qtA : qtB;
#pragma unroll
    for (int s = 0; s < 4; ++s)
      qf[pp][s] = *(const short8*)(Qfb + (size_t)qt * 2048 + s * 512 + lane * 8);
  }

  f32x16 o[2][2] = {};               // [part][d-half], O^T: col q, rows d
  f32x8 lacc[2] = {};                // vector l accumulators (summed at end)

  short8 kf[4], kn[4], vf[4];
  loadK4f(Kfb, 0, lane, kf);

  // segment 1: t in [0, qtA) -- both parts, no mask
  for (int t = 0; t < qtA; ++t) {
    loadV4f(Vfb, t, lane, vf);
    loadK4f(Kfb, t + 1, lane, kn);             // t+1 <= qtA <= 31: in-bounds
    attn_step<2, false>(0, kf, qf, q0, vf, lacc, o, ql, h);
#pragma unroll
    for (int s = 0; s < 4; ++s) kf[s] = kn[s];
  }
  // segment 2: t = qtA -- both parts, mask part A (B unmasked: qtA < qtB)
  {
    loadV4f(Vfb, qtA, lane, vf);
    loadK4f(Kfb, qtA + 1, lane, kn);           // qtA+1 <= 32: in-bounds
    attn_step<2, true>(qtA * 32, kf, qf, q0, vf, lacc, o, ql, h);
#pragma unroll
    for (int s = 0; s < 4; ++s) kf[s] = kn[s];
  }
  // segment 3: t in (qtA, qtB) -- part B only
  for (int t = qtA + 1; t < qtB; ++t) {
    loadV4f(Vfb, t, lane, vf);
    loadK4f(Kfb, t + 1, lane, kn);             // t+1 <= qtB <= 63: in-bounds
    attn_step<1, false>(0, kf, &qf[1], &q0[1], vf, &lacc[1], &o[1], ql, h);
#pragma unroll
    for (int s = 0; s < 4; ++s) kf[s] = kn[s];
  }
  // segment 4: t = qtB -- part B, masked, no prefetch
  {
    loadV4f(Vfb, qtB, lane, vf);
    attn_step<1, true>(qtB * 32, kf, &qf[1], &q0[1], vf, &lacc[1], &o[1], ql, h);
  }

  // epilogue: horizontal l-sum (once), cross-half merge (once), store
  const int b = bh >> 4, head = bh & 15;
#pragma unroll
  for (int pp = 0; pp < 2; ++pp) {
    float ls = ((lacc[pp][0] + lacc[pp][1]) + (lacc[pp][2] + lacc[pp][3])) +
               ((lacc[pp][4] + lacc[pp][5]) + (lacc[pp][6] + lacc[pp][7]));
    const float inv = 1.0f / redsum32(ls);
    unsigned short* Orow = O + ((size_t)(b * 2048 + q0[pp] + ql)) * 1024 + head * 64;
#pragma unroll
    for (int g = 0; g < 4; ++g) {
      {
        const unsigned int lo = pkbf(o[pp][0][g * 4 + 0] * inv, o[pp][0][g * 4 + 1] * inv);
        const unsigned int hi = pkbf(o[pp][0][g * 4 + 2] * inv, o[pp][0][g * 4 + 3] * inv);
        uint2 val; val.x = lo; val.y = hi;
        *(uint2*)(Orow + 8 * g + 4 * h) = val;
      }
      {
        const unsigned int lo = pkbf(o[pp][1][g * 4 + 0] * inv, o[pp][1][g * 4 + 1] * inv);
        const unsigned int hi = pkbf(o[pp][1][g * 4 + 2] * inv, o[pp][1][g * 4 + 3] * inv);
        uint2 val; val.x = lo; val.y = hi;
        *(uint2*)(Orow + 32 + 8 * g + 4 * h) = val;
      }
    }
  }
}

extern "C" void kernel_launch(void* const* d_in, const int* in_sizes, int n_in,
                              void* d_out, int out_size, void* d_ws, size_t ws_size,
                              hipStream_t stream) {
  (void)in_sizes; (void)n_in; (void)out_size; (void)ws_size;
  const float* x      = (const float*)d_in[0];
  const float* w_qkv  = (const float*)d_in[1];
  const float* w_proj = (const float*)d_in[2];
  float* out = (float*)d_out;
  char* ws = (char*)d_ws;

  unsigned short* x_bf   = (unsigned short*)(ws);              // 16 MB (reused as attn_out)
  unsigned short* wqT    = (unsigned short*)(ws + 16777216);   // 6 MB
  unsigned short* wpT    = (unsigned short*)(ws + 23068672);   // 2 MB
  unsigned short* Qfd    = (unsigned short*)(ws + 25165824);   // 16 MB (fragment order)
  unsigned short* Kfd    = (unsigned short*)(ws + 41943040);   // 16 MB (fragment order)
  unsigned short* Vfd    = (unsigned short*)(ws + 58720256);   // 16 MB (fragment order, fused)
  unsigned short* attn_o = x_bf;

  cvt_bf16_kernel<<<4096, 256, 0, stream>>>(x, x_bf, 8388608);
  transpose_w_kernel<<<dim3(96, 32), 256, 0, stream>>>(w_qkv, wqT, 1024, 3072);
  transpose_w_kernel<<<dim3(32, 32), 256, 0, stream>>>(w_proj, wpT, 1024, 1024);
  gemm_bt_kernel<8192, 3072, 1024, 0><<<dim3(24, 64), 256, 0, stream>>>(
      x_bf, wqT, Qfd, Kfd, Vfd, nullptr);
  attn_kernel<<<512, 256, 0, stream>>>(Qfd, Kfd, Vfd, attn_o);
  gemm_bt_kernel<8192, 1024, 1024, 1><<<dim3(8, 64), 256, 0, stream>>>(
      attn_o, wpT, nullptr, nullptr, nullptr, out);
}